// Round 3
// baseline (84.087 us; speedup 1.0000x reference)
//
#include <hip/hip_runtime.h>

// DAG reachability closure from node 0 (N=8192, <=2 children, -1 = leaf).
// Reference's N relaxation steps == transitive closure; we BFS to fixpoint.
//
// Single workgroup, 256 threads (4 waves) on one CU:
//   - edges staged interleaved in LDS as int2 (64 KB): one ds_read_b64/node
//   - reachable set: 256-word LDS bitmask; thread t owns word t (nodes 32t..32t+31)
//   - per-pass Gauss-Seidel: each thread re-scans its own word until locally
//     stable, so chains propagate multi-hop within a pass (fewer passes than
//     BFS depth); atomicOr scatters child bits (monotone -> races benign)
//   - termination: parity-flag protocol, 2 barriers/pass, race-free
//     (R2's single-flag reset had a read/reset race -> fixed here)
// Output: int32 0/1 (harness materializes the bool mask as int32).

#define NMAX 8192
#define NW   (NMAX / 32)   // 256 reach words
#define BLK  256

__global__ __launch_bounds__(BLK) void dag_reach_kernel(
    const int* __restrict__ left,
    const int* __restrict__ right,
    int* __restrict__ out,
    int n)
{
    __shared__ int2         sLR[NMAX];     // interleaved (left,right) per node
    __shared__ unsigned int reach[NW];     // reachability bitmask
    __shared__ int          flag[2];       // parity changed-flags

    const int tid = threadIdx.x;

    // ---- stage edges (vectorized int4 global reads, int2 LDS writes) ----
    {
        const int4* l4 = (const int4*)left;
        const int4* r4 = (const int4*)right;
        const int nv = n / 4;                      // n = 8192 -> 2048
        for (int i = tid; i < nv; i += BLK) {
            int4 l = l4[i];
            int4 r = r4[i];
            int b = i * 4;
            sLR[b + 0] = make_int2(l.x, r.x);
            sLR[b + 1] = make_int2(l.y, r.y);
            sLR[b + 2] = make_int2(l.z, r.z);
            sLR[b + 3] = make_int2(l.w, r.w);
        }
    }
    reach[tid] = (tid == 0) ? 1u : 0u;             // seed node 0
    if (tid < 2) flag[tid] = 0;
    __syncthreads();

    // ---- BFS to fixpoint ----
    unsigned int expd = 0u;                        // bits already expanded
    const int base = tid * 32;
    volatile unsigned int* vreach = (volatile unsigned int*)reach;

    for (int pass = 0; ; ++pass) {
        bool changed = false;

        // local Gauss-Seidel fixpoint on my word (catches same-pass arrivals)
        for (;;) {
            unsigned int pend = vreach[tid] & ~expd;
            if (!pend) break;
            changed = true;
            expd |= pend;
            do {
                int b = __ffs(pend) - 1;
                pend &= pend - 1;
                int2 lr = sLR[base + b];
                if (lr.x >= 0) atomicOr(&reach[lr.x >> 5], 1u << (lr.x & 31));
                if (lr.y >= 0) atomicOr(&reach[lr.y >> 5], 1u << (lr.y & 31));
            } while (pend);
        }

        if (changed)  flag[pass & 1] = 1;          // benign same-value race
        if (tid == 0) flag[(pass + 1) & 1] = 0;    // pre-reset next parity
        __syncthreads();                           // B1: sets visible
        int f = flag[pass & 1];
        __syncthreads();                           // B2: protect reads from
        if (!f) break;                             //     next pass's reset
    }

    // ---- write int32 0/1 mask (vectorized int4 stores) ----
    {
        int4* o4 = (int4*)out;
        const int nv = n / 4;
        for (int i = tid; i < nv; i += BLK) {
            unsigned int w = reach[i >> 3];
            int sh = (i & 7) * 4;
            int4 v;
            v.x = (int)((w >> (sh + 0)) & 1u);
            v.y = (int)((w >> (sh + 1)) & 1u);
            v.z = (int)((w >> (sh + 2)) & 1u);
            v.w = (int)((w >> (sh + 3)) & 1u);
            o4[i] = v;
        }
    }
}

extern "C" void kernel_launch(void* const* d_in, const int* in_sizes, int n_in,
                              void* d_out, int out_size, void* d_ws, size_t ws_size,
                              hipStream_t stream)
{
    // inputs: 0 = thresholds (f32, unused by reference), 1 = left, 2 = right
    const int* left  = (const int*)d_in[1];
    const int* right = (const int*)d_in[2];
    int* out = (int*)d_out;
    const int n = in_sizes[1];

    dag_reach_kernel<<<1, BLK, 0, stream>>>(left, right, out, n);
}